// Round 1
// baseline (614.903 us; speedup 1.0000x reference)
//
#include <hip/hip_runtime.h>

#define T_SEQ 512
#define U_TAGS 128
#define D_DIM 1024

// ---------------------------------------------------------------------------
// Kernel 1: logits = x @ kernel + bias, with left/right boundary adds fused.
// A: [32768,1024] fp32, Bk: [1024,128] fp32, C: [32768,128] fp32 (d_ws).
// 128x128 tile, 256 threads, 8x8 micro-tile, K-tile 16, reg-prefetch of the
// next global tile under compute.
// ---------------------------------------------------------------------------
__global__ __launch_bounds__(256) void crf_gemm(
    const float* __restrict__ A, const float* __restrict__ Bk,
    const float* __restrict__ bias, const float* __restrict__ lb,
    const float* __restrict__ rb, float* __restrict__ C) {
  __shared__ float As[16][132];  // [k][m], +4 pad
  __shared__ float Bs[16][132];  // [k][n], +4 pad
  const int tid = threadIdx.x;
  const int tx = tid & 15, ty = tid >> 4;
  const int row0 = blockIdx.x * 128;

  const int am = tid >> 2, ak = (tid & 3) << 2;   // A: 128m x 16k as float4
  const int bk = tid >> 5, bn = (tid & 31) << 2;  // B: 16k x 128n as float4

  float acc[8][8] = {};

  float4 a0 = *(const float4*)&A[(size_t)(row0 + am) * D_DIM + ak];
  float4 a1 = *(const float4*)&A[(size_t)(row0 + am + 64) * D_DIM + ak];
  float4 b0 = *(const float4*)&Bk[(size_t)bk * U_TAGS + bn];
  float4 b1 = *(const float4*)&Bk[(size_t)(bk + 8) * U_TAGS + bn];

  for (int k0 = 0; k0 < D_DIM; k0 += 16) {
    // store staged tile (A transposed to [k][m])
    As[ak + 0][am] = a0.x; As[ak + 1][am] = a0.y;
    As[ak + 2][am] = a0.z; As[ak + 3][am] = a0.w;
    As[ak + 0][am + 64] = a1.x; As[ak + 1][am + 64] = a1.y;
    As[ak + 2][am + 64] = a1.z; As[ak + 3][am + 64] = a1.w;
    *(float4*)&Bs[bk][bn] = b0;
    *(float4*)&Bs[bk + 8][bn] = b1;
    __syncthreads();
    if (k0 + 16 < D_DIM) {  // prefetch next tile into regs under compute
      a0 = *(const float4*)&A[(size_t)(row0 + am) * D_DIM + k0 + 16 + ak];
      a1 = *(const float4*)&A[(size_t)(row0 + am + 64) * D_DIM + k0 + 16 + ak];
      b0 = *(const float4*)&Bk[(size_t)(k0 + 16 + bk) * U_TAGS + bn];
      b1 = *(const float4*)&Bk[(size_t)(k0 + 16 + bk + 8) * U_TAGS + bn];
    }
#pragma unroll
    for (int kk = 0; kk < 16; ++kk) {
      float a[8], b[8];
      *(float4*)&a[0] = *(const float4*)&As[kk][ty * 8];
      *(float4*)&a[4] = *(const float4*)&As[kk][ty * 8 + 4];
      *(float4*)&b[0] = *(const float4*)&Bs[kk][tx * 8];
      *(float4*)&b[4] = *(const float4*)&Bs[kk][tx * 8 + 4];
#pragma unroll
      for (int r = 0; r < 8; ++r)
#pragma unroll
        for (int c = 0; c < 8; ++c) acc[r][c] = fmaf(a[r], b[c], acc[r][c]);
    }
    __syncthreads();
  }

#pragma unroll
  for (int r = 0; r < 8; ++r) {
    const int row = row0 + ty * 8 + r;
    const int t = row & (T_SEQ - 1);
    float o[8];
#pragma unroll
    for (int c = 0; c < 8; ++c) {
      float v = acc[r][c] + bias[tx * 8 + c];
      if (t == 0) v += lb[tx * 8 + c];
      if (t == T_SEQ - 1) v += rb[tx * 8 + c];
      o[c] = v;
    }
    *(float4*)&C[(size_t)row * U_TAGS + tx * 8] = *(float4*)&o[0];
    *(float4*)&C[(size_t)row * U_TAGS + tx * 8 + 4] = *(float4*)&o[4];
  }
}

// ---------------------------------------------------------------------------
// Kernel 2: fused Viterbi forward + backtrack. One block per batch element.
// 512 threads: thread = 4*j + seg; seg covers i in [seg*32, seg*32+32).
// trans column j cached in 32 VGPRs; v double-buffered in LDS; bp history
// (u8, 511x128) in LDS aliased over the one-time trans staging buffer.
// Cross-seg (4-lane) reductions via quad-perm DPP to stay off the LDS pipe.
// ---------------------------------------------------------------------------
__device__ __forceinline__ float fmax_dpp1(float m) {
  int i = __builtin_amdgcn_mov_dpp(__float_as_int(m), 0xB1, 0xF, 0xF, true);
  return fmaxf(m, __int_as_float(i));
}
__device__ __forceinline__ float fmax_dpp2(float m) {
  int i = __builtin_amdgcn_mov_dpp(__float_as_int(m), 0x4E, 0xF, 0xF, true);
  return fmaxf(m, __int_as_float(i));
}
__device__ __forceinline__ int imin_dpp1(int v) {
  int i = __builtin_amdgcn_mov_dpp(v, 0xB1, 0xF, 0xF, true);
  return v < i ? v : i;
}
__device__ __forceinline__ int imin_dpp2(int v) {
  int i = __builtin_amdgcn_mov_dpp(v, 0x4E, 0xF, 0xF, true);
  return v < i ? v : i;
}

__global__ __launch_bounds__(512) void crf_viterbi(
    const float* __restrict__ logits,  // [64, 512, 128]
    const float* __restrict__ trans,   // [128, 128]
    float* __restrict__ out) {         // [64, 512] fp32 tags
  __shared__ __align__(16) float vbuf[2][U_TAGS];
  __shared__ __align__(16) unsigned char bp[T_SEQ * U_TAGS];  // 64 KB
  __shared__ unsigned char tags[T_SEQ];
  __shared__ float red_v[8];
  __shared__ int red_i[8];

  const int b = blockIdx.x;
  const int tid = threadIdx.x;
  const int j = tid >> 2;
  const int seg = tid & 3;
  const float* lg_b = logits + (size_t)b * T_SEQ * U_TAGS;

  // Stage trans coalesced into LDS (region later reused as bp), then pull
  // this thread's 32 trans[i][j] values into registers.
  float* tstage = (float*)bp;
#pragma unroll
  for (int it = 0; it < 8; ++it)
    *(float4*)&tstage[(it * 512 + tid) * 4] =
        *(const float4*)&trans[(it * 512 + tid) * 4];
  __syncthreads();
  float tr[32];
#pragma unroll
  for (int e = 0; e < 32; ++e) tr[e] = tstage[(seg * 32 + e) * U_TAGS + j];
  if (tid < U_TAGS) vbuf[0][tid] = lg_b[tid];  // t=0 logits (lb already fused)
  __syncthreads();  // tr regs loaded -> bp region free; vbuf[0] published

  float lg = lg_b[U_TAGS + j];  // logit for t=1
  for (int t = 1; t < T_SEQ; ++t) {
    float lg_next = (t < T_SEQ - 1) ? lg_b[(size_t)(t + 1) * U_TAGS + j] : 0.0f;
    const float* vcur = &vbuf[(t - 1) & 1][seg * 32];
    float s[32];
#pragma unroll
    for (int q = 0; q < 8; ++q) {
      float4 vv = *(const float4*)&vcur[q * 4];
      s[q * 4 + 0] = vv.x + tr[q * 4 + 0];
      s[q * 4 + 1] = vv.y + tr[q * 4 + 1];
      s[q * 4 + 2] = vv.z + tr[q * 4 + 2];
      s[q * 4 + 3] = vv.w + tr[q * 4 + 3];
    }
    float m0 = s[0], m1 = s[1], m2 = s[2], m3 = s[3];
#pragma unroll
    for (int e = 4; e < 32; e += 4) {
      m0 = fmaxf(m0, s[e + 0]); m1 = fmaxf(m1, s[e + 1]);
      m2 = fmaxf(m2, s[e + 2]); m3 = fmaxf(m3, s[e + 3]);
    }
    float m = fmaxf(fmaxf(m0, m1), fmaxf(m2, m3));
    m = fmax_dpp1(m);
    m = fmax_dpp2(m);
    // first-index (jnp.argmax ties -> first) among exact-equal stored sums
    int el = 64;
#pragma unroll
    for (int e = 31; e >= 0; --e) el = (s[e] == m) ? e : el;
    int ic = (el < 64) ? (seg * 32 + el) : 1023;
    ic = imin_dpp1(ic);
    ic = imin_dpp2(ic);
    if (seg == 0) {
      vbuf[t & 1][j] = m + lg;
      bp[(t - 1) * U_TAGS + j] = (unsigned char)ic;
    }
    __syncthreads();
    lg = lg_next;
  }

  // last_tag = first argmax_j of final v (buffer (T_SEQ-1)&1 == 1)
  if (tid < U_TAGS) {
    float val = vbuf[(T_SEQ - 1) & 1][tid];
    int idx = tid;
#pragma unroll
    for (int off = 1; off < 64; off <<= 1) {
      float vo = __shfl_xor(val, off);
      int io = __shfl_xor(idx, off);
      if (vo > val || (vo == val && io < idx)) { val = vo; idx = io; }
    }
    if ((tid & 63) == 0) { red_v[tid >> 6] = val; red_i[tid >> 6] = idx; }
  }
  __syncthreads();
  if (tid == 0) {
    int tg = (red_v[1] > red_v[0]) ? red_i[1] : red_i[0];  // tie -> wave0 (lower j)
    tags[T_SEQ - 1] = (unsigned char)tg;
    for (int t = T_SEQ - 2; t >= 0; --t) {
      tg = bp[t * U_TAGS + tg];
      tags[t] = (unsigned char)tg;
    }
  }
  __syncthreads();
  out[(size_t)b * T_SEQ + tid] = (float)tags[tid];
}

// ---------------------------------------------------------------------------
extern "C" void kernel_launch(void* const* d_in, const int* in_sizes, int n_in,
                              void* d_out, int out_size, void* d_ws,
                              size_t ws_size, hipStream_t stream) {
  const float* x = (const float*)d_in[0];      // [64,512,1024]
  const float* kern = (const float*)d_in[1];   // [1024,128]
  const float* bias = (const float*)d_in[2];   // [128]
  const float* chain = (const float*)d_in[3];  // [128,128]
  const float* lb = (const float*)d_in[4];     // [128]
  const float* rb = (const float*)d_in[5];     // [128]
  float* out = (float*)d_out;                  // [64,512] fp32
  float* logits = (float*)d_ws;                // 32768*128 fp32 = 16.8 MB

  crf_gemm<<<256, 256, 0, stream>>>(x, kern, bias, lb, rb, logits);
  crf_viterbi<<<64, 512, 0, stream>>>(logits, chain, out);
}

// Round 2
// 602.347 us; speedup vs baseline: 1.0208x; 1.0208x over previous
//
#include <hip/hip_runtime.h>

#define T_SEQ 512
#define U_TAGS 128
#define D_DIM 1024

// ---------------------------------------------------------------------------
// Kernel 1: logits = x @ kernel + bias, boundary adds fused.
// 128x128 tile, 256 threads, 8x8 micro-tile (cols tx*4 and tx*4+64 so LDS
// b-reads are 2-way (free) instead of 4-way conflicted), K-tile 16,
// register prefetch of next global tile under compute.
// ---------------------------------------------------------------------------
__global__ __launch_bounds__(256) void crf_gemm(
    const float* __restrict__ A, const float* __restrict__ Bk,
    const float* __restrict__ bias, const float* __restrict__ lb,
    const float* __restrict__ rb, float* __restrict__ C) {
  __shared__ float As[16][132];  // [k][m], +4 pad
  __shared__ float Bs[16][132];  // [k][n], +4 pad
  const int tid = threadIdx.x;
  const int tx = tid & 15, ty = tid >> 4;
  const int row0 = blockIdx.x * 128;

  const int am = tid >> 2, ak = (tid & 3) << 2;   // A: 128m x 16k as float4
  const int bk = tid >> 5, bn = (tid & 31) << 2;  // B: 16k x 128n as float4

  float acc[8][8] = {};

  float4 a0 = *(const float4*)&A[(size_t)(row0 + am) * D_DIM + ak];
  float4 a1 = *(const float4*)&A[(size_t)(row0 + am + 64) * D_DIM + ak];
  float4 b0 = *(const float4*)&Bk[(size_t)bk * U_TAGS + bn];
  float4 b1 = *(const float4*)&Bk[(size_t)(bk + 8) * U_TAGS + bn];

  for (int k0 = 0; k0 < D_DIM; k0 += 16) {
    As[ak + 0][am] = a0.x; As[ak + 1][am] = a0.y;
    As[ak + 2][am] = a0.z; As[ak + 3][am] = a0.w;
    As[ak + 0][am + 64] = a1.x; As[ak + 1][am + 64] = a1.y;
    As[ak + 2][am + 64] = a1.z; As[ak + 3][am + 64] = a1.w;
    *(float4*)&Bs[bk][bn] = b0;
    *(float4*)&Bs[bk + 8][bn] = b1;
    __syncthreads();
    if (k0 + 16 < D_DIM) {
      a0 = *(const float4*)&A[(size_t)(row0 + am) * D_DIM + k0 + 16 + ak];
      a1 = *(const float4*)&A[(size_t)(row0 + am + 64) * D_DIM + k0 + 16 + ak];
      b0 = *(const float4*)&Bk[(size_t)(k0 + 16 + bk) * U_TAGS + bn];
      b1 = *(const float4*)&Bk[(size_t)(k0 + 16 + bk + 8) * U_TAGS + bn];
    }
#pragma unroll
    for (int kk = 0; kk < 16; ++kk) {
      float a[8], b[8];
      *(float4*)&a[0] = *(const float4*)&As[kk][ty * 8];
      *(float4*)&a[4] = *(const float4*)&As[kk][ty * 8 + 4];
      *(float4*)&b[0] = *(const float4*)&Bs[kk][tx * 4];        // 2-way, free
      *(float4*)&b[4] = *(const float4*)&Bs[kk][tx * 4 + 64];   // 2-way, free
#pragma unroll
      for (int r = 0; r < 8; ++r)
#pragma unroll
        for (int c = 0; c < 8; ++c) acc[r][c] = fmaf(a[r], b[c], acc[r][c]);
    }
    __syncthreads();
  }

#pragma unroll
  for (int r = 0; r < 8; ++r) {
    const int row = row0 + ty * 8 + r;
    const int t = row & (T_SEQ - 1);
    const int n0 = tx * 4, n1 = tx * 4 + 64;
    float o[8];
#pragma unroll
    for (int c = 0; c < 4; ++c) {
      float v = acc[r][c] + bias[n0 + c];
      if (t == 0) v += lb[n0 + c];
      if (t == T_SEQ - 1) v += rb[n0 + c];
      o[c] = v;
    }
#pragma unroll
    for (int c = 0; c < 4; ++c) {
      float v = acc[r][c + 4] + bias[n1 + c];
      if (t == 0) v += lb[n1 + c];
      if (t == T_SEQ - 1) v += rb[n1 + c];
      o[c + 4] = v;
    }
    *(float4*)&C[(size_t)row * U_TAGS + n0] = *(float4*)&o[0];
    *(float4*)&C[(size_t)row * U_TAGS + n1] = *(float4*)&o[4];
  }
}

// ---------------------------------------------------------------------------
// Kernel 2: fused Viterbi forward + backtrack.
// Thread = 4*j + seg. Hot loop uses a raw "lgkmcnt-only" barrier so global
// logit prefetch (2-deep pipeline) stays in flight across steps; vbuf is
// 4-way replicated + skewed (stride 136) so per-seg reads are conflict-free.
// Backtrack: per-wave chunk maps (all 128 seeds chased in parallel), compose,
// re-walk.
// ---------------------------------------------------------------------------
__device__ __forceinline__ void barrier_lds_only() {
  asm volatile("s_waitcnt lgkmcnt(0)\n\ts_barrier" ::: "memory");
}
__device__ __forceinline__ float fmax_dpp1(float m) {
  int i = __builtin_amdgcn_mov_dpp(__float_as_int(m), 0xB1, 0xF, 0xF, true);
  return fmaxf(m, __int_as_float(i));
}
__device__ __forceinline__ float fmax_dpp2(float m) {
  int i = __builtin_amdgcn_mov_dpp(__float_as_int(m), 0x4E, 0xF, 0xF, true);
  return fmaxf(m, __int_as_float(i));
}
__device__ __forceinline__ int imin_dpp1(int v) {
  int i = __builtin_amdgcn_mov_dpp(v, 0xB1, 0xF, 0xF, true);
  return v < i ? v : i;
}
__device__ __forceinline__ int imin_dpp2(int v) {
  int i = __builtin_amdgcn_mov_dpp(v, 0x4E, 0xF, 0xF, true);
  return v < i ? v : i;
}
__device__ __forceinline__ float max3f(float a, float b, float c) {
  return fmaxf(fmaxf(a, b), c);  // -> v_max3_f32
}

__global__ __launch_bounds__(512) void crf_viterbi(
    const float* __restrict__ logits,  // [64, 512, 128]
    const float* __restrict__ trans,   // [128, 128]
    float* __restrict__ out) {         // [64, 512] fp32 tags
  __shared__ __align__(16) float vbuf[2][4][136];             // 4 skewed copies
  __shared__ __align__(16) unsigned char bp[T_SEQ * U_TAGS];  // 64 KB
  __shared__ unsigned char tags[T_SEQ];
  __shared__ unsigned char M[8][U_TAGS];  // chunk maps
  __shared__ int seedL[8];
  __shared__ float red_v[8];
  __shared__ int red_i[8];

  const int b = blockIdx.x;
  const int tid = threadIdx.x;
  const int j = tid >> 2;
  const int seg = tid & 3;
  const float* lg_b = logits + (size_t)b * T_SEQ * U_TAGS;

  // Stage trans coalesced into LDS (region reused as bp), pull trans[i][j]
  // for i in [seg*32, seg*32+32) into registers.
  float* tstage = (float*)bp;
#pragma unroll
  for (int it = 0; it < 8; ++it)
    *(float4*)&tstage[(it * 512 + tid) * 4] =
        *(const float4*)&trans[(it * 512 + tid) * 4];
  __syncthreads();
  float tr[32];
#pragma unroll
  for (int e = 0; e < 32; ++e) tr[e] = tstage[(seg * 32 + e) * U_TAGS + j];
  if (tid < U_TAGS) {
    float v0 = lg_b[tid];  // t=0 logits (lb already fused)
#pragma unroll
    for (int cp = 0; cp < 4; ++cp) vbuf[0][cp][tid] = v0;
  }
  __syncthreads();  // tr regs loaded -> bp region free; vbuf[0] published

  float lgp0 = lg_b[1 * U_TAGS + j];  // for t=1
  float lgp1 = lg_b[2 * U_TAGS + j];  // for t=2
  for (int t = 1; t < T_SEQ; ++t) {
    int tp = t + 2; if (tp > T_SEQ - 1) tp = T_SEQ - 1;
    float lgnew = lg_b[(size_t)tp * U_TAGS + j];  // in flight across barriers

    // seg reads its own skewed copy: banks 8*seg + 4*q -> conflict-free
    const float* vrow = &vbuf[(t - 1) & 1][seg][seg * 32];
    float s[32];
#pragma unroll
    for (int q = 0; q < 8; ++q) {
      float4 vv = *(const float4*)&vrow[q * 4];
      s[q * 4 + 0] = vv.x + tr[q * 4 + 0];
      s[q * 4 + 1] = vv.y + tr[q * 4 + 1];
      s[q * 4 + 2] = vv.z + tr[q * 4 + 2];
      s[q * 4 + 3] = vv.w + tr[q * 4 + 3];
    }
    // max over 32 via max3 tree
    float a0 = max3f(s[0], s[1], s[2]),   a1 = max3f(s[3], s[4], s[5]);
    float a2 = max3f(s[6], s[7], s[8]),   a3 = max3f(s[9], s[10], s[11]);
    float a4 = max3f(s[12], s[13], s[14]), a5 = max3f(s[15], s[16], s[17]);
    float a6 = max3f(s[18], s[19], s[20]), a7 = max3f(s[21], s[22], s[23]);
    float a8 = max3f(s[24], s[25], s[26]), a9 = max3f(s[27], s[28], s[29]);
    float a10 = fmaxf(s[30], s[31]);
    float b0 = max3f(a0, a1, a2), b1 = max3f(a3, a4, a5);
    float b2 = max3f(a6, a7, a8), b3 = fmaxf(a9, a10);
    float m = fmaxf(max3f(b0, b1, b2), b3);
    m = fmax_dpp1(m);
    m = fmax_dpp2(m);
    // first-equal index: 4 independent 8-deep chains + min combine
    int e0 = 127, e1 = 127, e2 = 127, e3 = 127;
#pragma unroll
    for (int e = 7; e >= 0; --e) {
      e0 = (s[e] == m) ? e : e0;
      e1 = (s[8 + e] == m) ? 8 + e : e1;
      e2 = (s[16 + e] == m) ? 16 + e : e2;
      e3 = (s[24 + e] == m) ? 24 + e : e3;
    }
    int el = min(min(e0, e1), min(e2, e3));
    int ic = (el < 127) ? seg * 32 + el : 1023;
    ic = imin_dpp1(ic);
    ic = imin_dpp2(ic);
    if (seg == 0) {
      float vn = m + lgp0;
#pragma unroll
      for (int cp = 0; cp < 4; ++cp) vbuf[t & 1][cp][j] = vn;
      bp[(t - 1) * U_TAGS + j] = (unsigned char)ic;
    }
    lgp0 = lgp1;
    lgp1 = lgnew;
    barrier_lds_only();  // LDS visibility only; global loads stay in flight
  }

  // last_tag = first argmax_j of final v (buffer 1, copy 0)
  if (tid < U_TAGS) {
    float val = vbuf[1][0][tid];
    int idx = tid;
#pragma unroll
    for (int off = 1; off < 64; off <<= 1) {
      float vo = __shfl_xor(val, off);
      int io = __shfl_xor(idx, off);
      if (vo > val || (vo == val && io < idx)) { val = vo; idx = io; }
    }
    if ((tid & 63) == 0) { red_v[tid >> 6] = val; red_i[tid >> 6] = idx; }
  }
  __syncthreads();
  if (tid == 0) {
    int tg = (red_v[1] > red_v[0]) ? red_i[1] : red_i[0];
    tags[T_SEQ - 1] = (unsigned char)tg;
  }
  __syncthreads();

  // Backtrack pass A: each wave chases all 128 seeds through its 64-step
  // chunk (2 independent chains per lane, latency-parallel).
  const int w = tid >> 6, l = tid & 63;
  const int lo = w * 64;
  const int hi = (w == 7) ? (T_SEQ - 2) : (w * 64 + 63);
  {
    int c0 = l, c1 = l + 64;
    for (int t = hi; t >= lo; --t) {
      c0 = bp[t * U_TAGS + c0];
      c1 = bp[t * U_TAGS + c1];
    }
    M[w][l] = (unsigned char)c0;
    M[w][l + 64] = (unsigned char)c1;
  }
  __syncthreads();
  if (tid == 0) {
    int sd = tags[T_SEQ - 1];
    seedL[7] = sd;
    for (int w2 = 7; w2 >= 1; --w2) { sd = M[w2][sd]; seedL[w2 - 1] = sd; }
  }
  __syncthreads();
  // Pass B: re-walk each chunk with its known entry tag, record tags.
  if (l == 0) {
    int cur = seedL[w];
    for (int t = hi; t >= lo; --t) {
      cur = bp[t * U_TAGS + cur];
      tags[t] = (unsigned char)cur;
    }
  }
  __syncthreads();
  out[(size_t)b * T_SEQ + tid] = (float)tags[tid];
}

// ---------------------------------------------------------------------------
extern "C" void kernel_launch(void* const* d_in, const int* in_sizes, int n_in,
                              void* d_out, int out_size, void* d_ws,
                              size_t ws_size, hipStream_t stream) {
  const float* x = (const float*)d_in[0];      // [64,512,1024]
  const float* kern = (const float*)d_in[1];   // [1024,128]
  const float* bias = (const float*)d_in[2];   // [128]
  const float* chain = (const float*)d_in[3];  // [128,128]
  const float* lb = (const float*)d_in[4];     // [128]
  const float* rb = (const float*)d_in[5];     // [128]
  float* out = (float*)d_out;                  // [64,512] fp32
  float* logits = (float*)d_ws;                // 32768*128 fp32 = 16.8 MB

  crf_gemm<<<256, 256, 0, stream>>>(x, kern, bias, lb, rb, logits);
  crf_viterbi<<<64, 512, 0, stream>>>(logits, chain, out);
}

// Round 3
// 591.402 us; speedup vs baseline: 1.0397x; 1.0185x over previous
//
#include <hip/hip_runtime.h>

#define T_SEQ 512
#define U_TAGS 128
#define D_DIM 1024
#define M_ROWS (64 * T_SEQ)  // 32768

// ---------------------------------------------------------------------------
// Kernel 1a: partial GEMM over half of K. Grid (256 M-tiles, 2 K-halves) =
// 512 blocks -> 2 blocks/CU -> 2 waves/SIMD (latency hiding; round-2 version
// ran 1 wave/SIMD and stalled at 268 us vs the 82 us LDS-pipe floor).
// 128x128 tile, 256 threads, 8x8 micro (cols tx*4 / tx*4+64: 2-way LDS reads,
// free), K-tile 16, register prefetch of next tile.
// ---------------------------------------------------------------------------
__global__ __launch_bounds__(256) void crf_gemm_half(
    const float* __restrict__ A, const float* __restrict__ Bk,
    float* __restrict__ Cpart) {
  __shared__ float As[16][132];
  __shared__ float Bs[16][132];
  const int tid = threadIdx.x;
  const int tx = tid & 15, ty = tid >> 4;
  const int row0 = blockIdx.x * 128;
  const int kbase = blockIdx.y * (D_DIM / 2);

  const int am = tid >> 2, ak = (tid & 3) << 2;
  const int bk = tid >> 5, bn = (tid & 31) << 2;

  float acc[8][8] = {};

  float4 a0 = *(const float4*)&A[(size_t)(row0 + am) * D_DIM + kbase + ak];
  float4 a1 = *(const float4*)&A[(size_t)(row0 + am + 64) * D_DIM + kbase + ak];
  float4 b0 = *(const float4*)&Bk[(size_t)(kbase + bk) * U_TAGS + bn];
  float4 b1 = *(const float4*)&Bk[(size_t)(kbase + bk + 8) * U_TAGS + bn];

  for (int k0 = 0; k0 < D_DIM / 2; k0 += 16) {
    As[ak + 0][am] = a0.x; As[ak + 1][am] = a0.y;
    As[ak + 2][am] = a0.z; As[ak + 3][am] = a0.w;
    As[ak + 0][am + 64] = a1.x; As[ak + 1][am + 64] = a1.y;
    As[ak + 2][am + 64] = a1.z; As[ak + 3][am + 64] = a1.w;
    *(float4*)&Bs[bk][bn] = b0;
    *(float4*)&Bs[bk + 8][bn] = b1;
    __syncthreads();
    if (k0 + 16 < D_DIM / 2) {
      const int kn = kbase + k0 + 16;
      a0 = *(const float4*)&A[(size_t)(row0 + am) * D_DIM + kn + ak];
      a1 = *(const float4*)&A[(size_t)(row0 + am + 64) * D_DIM + kn + ak];
      b0 = *(const float4*)&Bk[(size_t)(kn + bk) * U_TAGS + bn];
      b1 = *(const float4*)&Bk[(size_t)(kn + bk + 8) * U_TAGS + bn];
    }
#pragma unroll
    for (int kk = 0; kk < 16; ++kk) {
      float a[8], b[8];
      *(float4*)&a[0] = *(const float4*)&As[kk][ty * 8];
      *(float4*)&a[4] = *(const float4*)&As[kk][ty * 8 + 4];
      *(float4*)&b[0] = *(const float4*)&Bs[kk][tx * 4];
      *(float4*)&b[4] = *(const float4*)&Bs[kk][tx * 4 + 64];
#pragma unroll
      for (int r = 0; r < 8; ++r)
#pragma unroll
        for (int c = 0; c < 8; ++c) acc[r][c] = fmaf(a[r], b[c], acc[r][c]);
    }
    __syncthreads();
  }

  float* Cp = Cpart + (size_t)blockIdx.y * M_ROWS * U_TAGS;
#pragma unroll
  for (int r = 0; r < 8; ++r) {
    const int row = row0 + ty * 8 + r;
    *(float4*)&Cp[(size_t)row * U_TAGS + tx * 4] = *(float4*)&acc[r][0];
    *(float4*)&Cp[(size_t)row * U_TAGS + tx * 4 + 64] = *(float4*)&acc[r][4];
  }
}

// ---------------------------------------------------------------------------
// Kernel 1b: logits = p0 + p1 + bias (+boundaries), written in place over p0.
// Fixed order -> bitwise deterministic. One float4 per thread.
// ---------------------------------------------------------------------------
__global__ __launch_bounds__(256) void crf_combine(
    float* __restrict__ p, const float* __restrict__ bias,
    const float* __restrict__ lb, const float* __restrict__ rb) {
  const int i = blockIdx.x * 256 + threadIdx.x;  // float4 index
  const int row = i >> 5;
  const int col = (i & 31) << 2;
  const int t = row & (T_SEQ - 1);
  const float* p1 = p + (size_t)M_ROWS * U_TAGS;
  float4 v0 = *(const float4*)&p[(size_t)i * 4];
  float4 v1 = *(const float4*)&p1[(size_t)i * 4];
  float4 bb = *(const float4*)&bias[col];
  float4 o;
  o.x = v0.x + v1.x + bb.x; o.y = v0.y + v1.y + bb.y;
  o.z = v0.z + v1.z + bb.z; o.w = v0.w + v1.w + bb.w;
  if (t == 0) {
    float4 l = *(const float4*)&lb[col];
    o.x += l.x; o.y += l.y; o.z += l.z; o.w += l.w;
  }
  if (t == T_SEQ - 1) {
    float4 r = *(const float4*)&rb[col];
    o.x += r.x; o.y += r.y; o.z += r.z; o.w += r.w;
  }
  *(float4*)&p[(size_t)i * 4] = o;
}

// ---------------------------------------------------------------------------
// Fallback single-K GEMM (used only if ws_size < 2 partial buffers).
// ---------------------------------------------------------------------------
__global__ __launch_bounds__(256) void crf_gemm(
    const float* __restrict__ A, const float* __restrict__ Bk,
    const float* __restrict__ bias, const float* __restrict__ lb,
    const float* __restrict__ rb, float* __restrict__ C) {
  __shared__ float As[16][132];
  __shared__ float Bs[16][132];
  const int tid = threadIdx.x;
  const int tx = tid & 15, ty = tid >> 4;
  const int row0 = blockIdx.x * 128;
  const int am = tid >> 2, ak = (tid & 3) << 2;
  const int bk = tid >> 5, bn = (tid & 31) << 2;
  float acc[8][8] = {};
  float4 a0 = *(const float4*)&A[(size_t)(row0 + am) * D_DIM + ak];
  float4 a1 = *(const float4*)&A[(size_t)(row0 + am + 64) * D_DIM + ak];
  float4 b0 = *(const float4*)&Bk[(size_t)bk * U_TAGS + bn];
  float4 b1 = *(const float4*)&Bk[(size_t)(bk + 8) * U_TAGS + bn];
  for (int k0 = 0; k0 < D_DIM; k0 += 16) {
    As[ak + 0][am] = a0.x; As[ak + 1][am] = a0.y;
    As[ak + 2][am] = a0.z; As[ak + 3][am] = a0.w;
    As[ak + 0][am + 64] = a1.x; As[ak + 1][am + 64] = a1.y;
    As[ak + 2][am + 64] = a1.z; As[ak + 3][am + 64] = a1.w;
    *(float4*)&Bs[bk][bn] = b0;
    *(float4*)&Bs[bk + 8][bn] = b1;
    __syncthreads();
    if (k0 + 16 < D_DIM) {
      a0 = *(const float4*)&A[(size_t)(row0 + am) * D_DIM + k0 + 16 + ak];
      a1 = *(const float4*)&A[(size_t)(row0 + am + 64) * D_DIM + k0 + 16 + ak];
      b0 = *(const float4*)&Bk[(size_t)(k0 + 16 + bk) * U_TAGS + bn];
      b1 = *(const float4*)&Bk[(size_t)(k0 + 16 + bk + 8) * U_TAGS + bn];
    }
#pragma unroll
    for (int kk = 0; kk < 16; ++kk) {
      float a[8], b[8];
      *(float4*)&a[0] = *(const float4*)&As[kk][ty * 8];
      *(float4*)&a[4] = *(const float4*)&As[kk][ty * 8 + 4];
      *(float4*)&b[0] = *(const float4*)&Bs[kk][tx * 4];
      *(float4*)&b[4] = *(const float4*)&Bs[kk][tx * 4 + 64];
#pragma unroll
      for (int r = 0; r < 8; ++r)
#pragma unroll
        for (int c = 0; c < 8; ++c) acc[r][c] = fmaf(a[r], b[c], acc[r][c]);
    }
    __syncthreads();
  }
#pragma unroll
  for (int r = 0; r < 8; ++r) {
    const int row = row0 + ty * 8 + r;
    const int t = row & (T_SEQ - 1);
    const int n0 = tx * 4, n1 = tx * 4 + 64;
    float o[8];
#pragma unroll
    for (int c = 0; c < 4; ++c) {
      float v = acc[r][c] + bias[n0 + c];
      if (t == 0) v += lb[n0 + c];
      if (t == T_SEQ - 1) v += rb[n0 + c];
      o[c] = v;
    }
#pragma unroll
    for (int c = 0; c < 4; ++c) {
      float v = acc[r][c + 4] + bias[n1 + c];
      if (t == 0) v += lb[n1 + c];
      if (t == T_SEQ - 1) v += rb[n1 + c];
      o[c + 4] = v;
    }
    *(float4*)&C[(size_t)row * U_TAGS + n0] = *(float4*)&o[0];
    *(float4*)&C[(size_t)row * U_TAGS + n1] = *(float4*)&o[4];
  }
}

// ---------------------------------------------------------------------------
// Kernel 2: fused Viterbi forward + backtrack (unchanged from round 2).
// ---------------------------------------------------------------------------
__device__ __forceinline__ void barrier_lds_only() {
  asm volatile("s_waitcnt lgkmcnt(0)\n\ts_barrier" ::: "memory");
}
__device__ __forceinline__ float fmax_dpp1(float m) {
  int i = __builtin_amdgcn_mov_dpp(__float_as_int(m), 0xB1, 0xF, 0xF, true);
  return fmaxf(m, __int_as_float(i));
}
__device__ __forceinline__ float fmax_dpp2(float m) {
  int i = __builtin_amdgcn_mov_dpp(__float_as_int(m), 0x4E, 0xF, 0xF, true);
  return fmaxf(m, __int_as_float(i));
}
__device__ __forceinline__ int imin_dpp1(int v) {
  int i = __builtin_amdgcn_mov_dpp(v, 0xB1, 0xF, 0xF, true);
  return v < i ? v : i;
}
__device__ __forceinline__ int imin_dpp2(int v) {
  int i = __builtin_amdgcn_mov_dpp(v, 0x4E, 0xF, 0xF, true);
  return v < i ? v : i;
}
__device__ __forceinline__ float max3f(float a, float b, float c) {
  return fmaxf(fmaxf(a, b), c);
}

__global__ __launch_bounds__(512) void crf_viterbi(
    const float* __restrict__ logits,  // [64, 512, 128]
    const float* __restrict__ trans,   // [128, 128]
    float* __restrict__ out) {         // [64, 512] fp32 tags
  __shared__ __align__(16) float vbuf[2][4][136];
  __shared__ __align__(16) unsigned char bp[T_SEQ * U_TAGS];
  __shared__ unsigned char tags[T_SEQ];
  __shared__ unsigned char M[8][U_TAGS];
  __shared__ int seedL[8];
  __shared__ float red_v[8];
  __shared__ int red_i[8];

  const int b = blockIdx.x;
  const int tid = threadIdx.x;
  const int j = tid >> 2;
  const int seg = tid & 3;
  const float* lg_b = logits + (size_t)b * T_SEQ * U_TAGS;

  float* tstage = (float*)bp;
#pragma unroll
  for (int it = 0; it < 8; ++it)
    *(float4*)&tstage[(it * 512 + tid) * 4] =
        *(const float4*)&trans[(it * 512 + tid) * 4];
  __syncthreads();
  float tr[32];
#pragma unroll
  for (int e = 0; e < 32; ++e) tr[e] = tstage[(seg * 32 + e) * U_TAGS + j];
  if (tid < U_TAGS) {
    float v0 = lg_b[tid];
#pragma unroll
    for (int cp = 0; cp < 4; ++cp) vbuf[0][cp][tid] = v0;
  }
  __syncthreads();

  float lgp0 = lg_b[1 * U_TAGS + j];
  float lgp1 = lg_b[2 * U_TAGS + j];
  for (int t = 1; t < T_SEQ; ++t) {
    int tp = t + 2; if (tp > T_SEQ - 1) tp = T_SEQ - 1;
    float lgnew = lg_b[(size_t)tp * U_TAGS + j];

    const float* vrow = &vbuf[(t - 1) & 1][seg][seg * 32];
    float s[32];
#pragma unroll
    for (int q = 0; q < 8; ++q) {
      float4 vv = *(const float4*)&vrow[q * 4];
      s[q * 4 + 0] = vv.x + tr[q * 4 + 0];
      s[q * 4 + 1] = vv.y + tr[q * 4 + 1];
      s[q * 4 + 2] = vv.z + tr[q * 4 + 2];
      s[q * 4 + 3] = vv.w + tr[q * 4 + 3];
    }
    float a0 = max3f(s[0], s[1], s[2]),   a1 = max3f(s[3], s[4], s[5]);
    float a2 = max3f(s[6], s[7], s[8]),   a3 = max3f(s[9], s[10], s[11]);
    float a4 = max3f(s[12], s[13], s[14]), a5 = max3f(s[15], s[16], s[17]);
    float a6 = max3f(s[18], s[19], s[20]), a7 = max3f(s[21], s[22], s[23]);
    float a8 = max3f(s[24], s[25], s[26]), a9 = max3f(s[27], s[28], s[29]);
    float a10 = fmaxf(s[30], s[31]);
    float b0 = max3f(a0, a1, a2), b1 = max3f(a3, a4, a5);
    float b2 = max3f(a6, a7, a8), b3 = fmaxf(a9, a10);
    float m = fmaxf(max3f(b0, b1, b2), b3);
    m = fmax_dpp1(m);
    m = fmax_dpp2(m);
    int e0 = 127, e1 = 127, e2 = 127, e3 = 127;
#pragma unroll
    for (int e = 7; e >= 0; --e) {
      e0 = (s[e] == m) ? e : e0;
      e1 = (s[8 + e] == m) ? 8 + e : e1;
      e2 = (s[16 + e] == m) ? 16 + e : e2;
      e3 = (s[24 + e] == m) ? 24 + e : e3;
    }
    int el = min(min(e0, e1), min(e2, e3));
    int ic = (el < 127) ? seg * 32 + el : 1023;
    ic = imin_dpp1(ic);
    ic = imin_dpp2(ic);
    if (seg == 0) {
      float vn = m + lgp0;
#pragma unroll
      for (int cp = 0; cp < 4; ++cp) vbuf[t & 1][cp][j] = vn;
      bp[(t - 1) * U_TAGS + j] = (unsigned char)ic;
    }
    lgp0 = lgp1;
    lgp1 = lgnew;
    barrier_lds_only();
  }

  if (tid < U_TAGS) {
    float val = vbuf[1][0][tid];
    int idx = tid;
#pragma unroll
    for (int off = 1; off < 64; off <<= 1) {
      float vo = __shfl_xor(val, off);
      int io = __shfl_xor(idx, off);
      if (vo > val || (vo == val && io < idx)) { val = vo; idx = io; }
    }
    if ((tid & 63) == 0) { red_v[tid >> 6] = val; red_i[tid >> 6] = idx; }
  }
  __syncthreads();
  if (tid == 0) {
    int tg = (red_v[1] > red_v[0]) ? red_i[1] : red_i[0];
    tags[T_SEQ - 1] = (unsigned char)tg;
  }
  __syncthreads();

  const int w = tid >> 6, l = tid & 63;
  const int lo = w * 64;
  const int hi = (w == 7) ? (T_SEQ - 2) : (w * 64 + 63);
  {
    int c0 = l, c1 = l + 64;
    for (int t = hi; t >= lo; --t) {
      c0 = bp[t * U_TAGS + c0];
      c1 = bp[t * U_TAGS + c1];
    }
    M[w][l] = (unsigned char)c0;
    M[w][l + 64] = (unsigned char)c1;
  }
  __syncthreads();
  if (tid == 0) {
    int sd = tags[T_SEQ - 1];
    seedL[7] = sd;
    for (int w2 = 7; w2 >= 1; --w2) { sd = M[w2][sd]; seedL[w2 - 1] = sd; }
  }
  __syncthreads();
  if (l == 0) {
    int cur = seedL[w];
    for (int t = hi; t >= lo; --t) {
      cur = bp[t * U_TAGS + cur];
      tags[t] = (unsigned char)cur;
    }
  }
  __syncthreads();
  out[(size_t)b * T_SEQ + tid] = (float)tags[tid];
}

// ---------------------------------------------------------------------------
extern "C" void kernel_launch(void* const* d_in, const int* in_sizes, int n_in,
                              void* d_out, int out_size, void* d_ws,
                              size_t ws_size, hipStream_t stream) {
  const float* x = (const float*)d_in[0];
  const float* kern = (const float*)d_in[1];
  const float* bias = (const float*)d_in[2];
  const float* chain = (const float*)d_in[3];
  const float* lb = (const float*)d_in[4];
  const float* rb = (const float*)d_in[5];
  float* out = (float*)d_out;
  float* logits = (float*)d_ws;  // final logits live at ws base in both paths

  const size_t part = (size_t)M_ROWS * U_TAGS * sizeof(float);  // 16.8 MB
  if (ws_size >= 2 * part) {
    crf_gemm_half<<<dim3(256, 2), 256, 0, stream>>>(x, kern, logits);
    crf_combine<<<(M_ROWS * U_TAGS / 4 + 255) / 256, 256, 0, stream>>>(
        logits, bias, lb, rb);
  } else {
    crf_gemm<<<256, 256, 0, stream>>>(x, kern, bias, lb, rb, logits);
  }
  crf_viterbi<<<64, 512, 0, stream>>>(logits, chain, out);
}